// Round 12
// baseline (243.613 us; speedup 1.0000x reference)
//
#include <hip/hip_runtime.h>
#include <math.h>

// Chamfer k-NN (k=16, L2), R11: occupancy via 128-thread blocks (2048 blocks
// = 8 blocks/CU, same total selection work as R10) + last-block fused merge
// (device-fence + atomic ticket; removes the merge dispatch).
// kernel0 (pack): pred4/tgt4 packing, zero out[0] and ticket counters.
// kernel1 (knn):  grid (64 q-chunks x 8 slices x B*2); s_load refs; QUAD gate;
//                 32-deep LDS queue; batched bitonic drains; 8th finisher
//                 block per (z,qchunk) merges 8 sorted 16-lists -> atomicAdd.

#define INFV    3.0e38f
#define NSLICE  8
#define QDEPTH  32
#define BT      128         // threads per block

__device__ __forceinline__ void ce(float& a, float& b) {
    float lo = fminf(a, b);
    b = fmaxf(a, b);
    a = lo;
}

// bitonic merge-sort of a bitonic 16-seq (stages 8,4,2,1 = 32 CE), ascending
__device__ __forceinline__ void bitonic16(float (&s)[16]) {
    ce(s[0],s[8]);  ce(s[1],s[9]);  ce(s[2],s[10]); ce(s[3],s[11]);
    ce(s[4],s[12]); ce(s[5],s[13]); ce(s[6],s[14]); ce(s[7],s[15]);
    ce(s[0],s[4]);  ce(s[1],s[5]);  ce(s[2],s[6]);  ce(s[3],s[7]);
    ce(s[8],s[12]); ce(s[9],s[13]); ce(s[10],s[14]);ce(s[11],s[15]);
    ce(s[0],s[2]);  ce(s[1],s[3]);  ce(s[4],s[6]);  ce(s[5],s[7]);
    ce(s[8],s[10]); ce(s[9],s[11]); ce(s[12],s[14]);ce(s[13],s[15]);
    ce(s[0],s[1]);  ce(s[2],s[3]);  ce(s[4],s[5]);  ce(s[6],s[7]);
    ce(s[8],s[9]);  ce(s[10],s[11]);ce(s[12],s[13]);ce(s[14],s[15]);
}

// Merge up to 8 queued values (qb[(base+i)*BT], i<cnt-base) into sorted s[16].
__device__ __forceinline__ void drain_batch(float (&s)[16], const float* qb,
                                            int base, int cnt)
{
    float q[8];
#pragma unroll
    for (int i = 0; i < 8; ++i) {
        float v = qb[(base + i) * BT];
        q[i] = (base + i < cnt) ? v : INFV;
    }
    // sort8 ascending — Batcher odd-even, 19 CE
    ce(q[0],q[1]); ce(q[2],q[3]); ce(q[4],q[5]); ce(q[6],q[7]);
    ce(q[0],q[2]); ce(q[1],q[3]); ce(q[4],q[6]); ce(q[5],q[7]);
    ce(q[1],q[2]); ce(q[5],q[6]);
    ce(q[0],q[4]); ce(q[1],q[5]); ce(q[2],q[6]); ce(q[3],q[7]);
    ce(q[2],q[4]); ce(q[3],q[5]);
    ce(q[1],q[2]); ce(q[3],q[4]); ce(q[5],q[6]);
    // bitonic halver vs sorted s[16]: s[8+i] = min(s[8+i], q[7-i]) -> bitonic
#pragma unroll
    for (int i = 0; i < 8; ++i) s[8 + i] = fminf(s[8 + i], q[7 - i]);
    bitonic16(s);
}

__global__ __launch_bounds__(256) void pack_kernel(
    const float* __restrict__ src, const float* __restrict__ tgt,
    const float* __restrict__ flow,
    float4* __restrict__ pred4, float4* __restrict__ tgt4,
    float* __restrict__ out, int* __restrict__ tickets, int nkeys,
    int BN, int BM)
{
    int i = blockIdx.x * 256 + threadIdx.x;
    if (i == 0) out[0] = 0.0f;                 // replaces memset (poisoned 0xAA)
    if (i < nkeys) tickets[i] = 0;             // zero merge tickets each launch
    if (i < BN) {
        float x = src[3 * i + 0] + flow[3 * i + 0];
        float y = src[3 * i + 1] + flow[3 * i + 1];
        float z = src[3 * i + 2] + flow[3 * i + 2];
        pred4[i] = make_float4(x, y, z, fmaf(x, x, fmaf(y, y, z * z)));
    }
    if (i < BM) {
        float x = tgt[3 * i + 0];
        float y = tgt[3 * i + 1];
        float z = tgt[3 * i + 2];
        tgt4[i] = make_float4(x, y, z, fmaf(x, x, fmaf(y, y, z * z)));
    }
}

__global__ __launch_bounds__(BT, 4) void knn_slice_kernel(
    const float4* __restrict__ pred4,  // [B][N] (x,y,z,|p|^2)
    const float4* __restrict__ tgt4,   // [B][M]
    float* __restrict__ topk,          // [NSLICE][16][T], true d2, sorted asc
    int* __restrict__ tickets,         // [4*gridDim.x]
    float* __restrict__ out,
    int N, int M, int T, float scale)
{
    __shared__ float qbuf[QDEPTH * BT];   // 16 KB per-thread queues, stride BT
    __shared__ int   lastFlag;
    __shared__ float wsum[BT / 64];

    const int tid   = threadIdx.x;
    const int slice = blockIdx.y;
    const int z     = blockIdx.z;          // b*2 + dir
    const int b     = z >> 1, dir = z & 1;

    const int nq   = dir ? M : N;
    const int nref = dir ? N : M;
    const int qi   = blockIdx.x * BT + tid;
    const long instBase = (long)((z >= 1 ? N : 0) + (z >= 2 ? M : 0) + (z >= 3 ? N : 0));

    const float4* qp = (dir ? tgt4 : pred4) + (size_t)b * nq;
    const float4* rp = (dir ? pred4 : tgt4) + (size_t)b * nref;

    const int slen = nref / NSLICE;
    const int base = slice * slen;
    const int jend = (slice == NSLICE - 1) ? (nref - base) : slen;
    const float4* rs = rp + base;          // wave-uniform ref stream -> s_load

    const bool valid = qi < nq;
    float nx = 0.f, ny = 0.f, nz = 0.f, q2 = 0.f;
    if (valid) {
        float4 q = qp[qi];
        nx = -2.0f * q.x; ny = -2.0f * q.y; nz = -2.0f * q.z; q2 = q.w;
    }

    float s[16];
#pragma unroll
    for (int i = 0; i < 16; ++i) s[i] = INFV;
    float tau = valid ? INFV : -INFV;      // invalid lanes never enqueue
    int   cnt = 0;
    const float* qb_tid = qbuf + tid;

    auto dist = [&](const float4& p) -> float {
        return fmaf(nx, p.x, fmaf(ny, p.y, fmaf(nz, p.z, p.w)));
    };

#define DRAIN_ALL() {                                               \
        drain_batch(s, qb_tid, 0, cnt);                             \
        if (__ballot(cnt >  8)) drain_batch(s, qb_tid,  8, cnt);    \
        if (__ballot(cnt > 16)) drain_batch(s, qb_tid, 16, cnt);    \
        if (__ballot(cnt > 24)) drain_batch(s, qb_tid, 24, cnt);    \
        cnt = 0;                                                    \
        tau = valid ? s[15] : -INFV;                                \
    }

#define ENQ(c) { qbuf[cnt * BT + tid] = (c); cnt += ((c) < tau) ? 1 : 0; }

#define QUAD(w0, w1, w2, w3) {                                      \
        float c0 = dist(w0), c1 = dist(w1);                         \
        float c2 = dist(w2), c3 = dist(w3);                         \
        float m = fminf(fminf(c0, c1), fminf(c2, c3));              \
        if (m < tau) { ENQ(c0) ENQ(c1) ENQ(c2) ENQ(c3) }           \
    }

#define PROC8(w) {                                                  \
        QUAD(w[0], w[1], w[2], w[3])                                \
        QUAD(w[4], w[5], w[6], w[7])                                \
        if (__ballot(cnt >= QDEPTH - 7)) DRAIN_ALL();               \
    }

    const int ngrp = jend >> 3;
    const int gmax = ngrp & ~1;            // even count for the 2x-unrolled loop
    float4 wA[8], wB[8];                   // scalarized -> SGPR tuples
    if (gmax > 0) {
#pragma unroll
        for (int u = 0; u < 8; ++u) wA[u] = rs[u];
        for (int g = 0; g < gmax; g += 2) {
            {   // prefetch group g+1 (uniform addr -> s_load) during group g
                const float4* tp = rs + (size_t)(g + 1) * 8;
#pragma unroll
                for (int u = 0; u < 8; ++u) wB[u] = tp[u];
            }
            PROC8(wA)
            {   // prefetch group g+2 (clamped) during group g+1
                const float4* tp = rs + (size_t)((g + 2 < gmax) ? g + 2 : g) * 8;
#pragma unroll
                for (int u = 0; u < 8; ++u) wA[u] = tp[u];
            }
            PROC8(wB)
        }
    }
    for (int j = gmax * 8; j < jend; ++j) {    // generic tail
        float4 r = rs[j];
        float c = dist(r);
        if (c < tau) ENQ(c)
        if (__ballot(cnt >= QDEPTH - 7)) DRAIN_ALL();
    }
    if (__ballot(cnt > 0)) DRAIN_ALL();        // final

#undef PROC8
#undef QUAD
#undef ENQ
#undef DRAIN_ALL

    const long inst = instBase + qi;
    if (valid) {
        // transposed layout: topk[(slice*16 + i)*T + inst] — lane-coalesced
        float* o = topk + (size_t)slice * 16 * T + inst;
#pragma unroll
        for (int i = 0; i < 16; ++i) o[(size_t)i * T] = s[i] + q2;  // true d2
    }

    // ---- last-block fused merge (atomic ticket per (z, qchunk)) ----
    __threadfence();                       // release: publish topk writes
    if (tid == 0) {
        int key = z * gridDim.x + blockIdx.x;
        lastFlag = (atomicAdd(&tickets[key], 1) == NSLICE - 1) ? 1 : 0;
    }
    __syncthreads();
    if (lastFlag) {
        __threadfence();                   // acquire: see other blocks' topk
        float acc = 0.0f;
        if (valid) {
            float t[16];
#pragma unroll
            for (int i = 0; i < 16; ++i)
                t[i] = topk[(size_t)i * T + inst];       // slice 0, sorted asc
            for (int sl = 1; sl < NSLICE; ++sl) {
                const float* q = topk + (size_t)sl * 16 * T + inst;
#pragma unroll
                for (int i = 0; i < 16; ++i)
                    t[i] = fminf(t[i], q[(size_t)(15 - i) * T]);  // halver
                if (sl < NSLICE - 1) bitonic16(t);       // prep next halver
            }
            float sum = 0.0f;
#pragma unroll
            for (int i = 0; i < 16; ++i) sum += sqrtf(fmaxf(t[i], 0.0f));
            acc = sum * (1.0f / 16.0f);
        }
#pragma unroll
        for (int off = 32; off > 0; off >>= 1) acc += __shfl_down(acc, off);
        if ((tid & 63) == 0) wsum[tid >> 6] = acc;
        __syncthreads();
        if (tid == 0) atomicAdd(out, (wsum[0] + wsum[1]) * scale);
    }
}

extern "C" void kernel_launch(void* const* d_in, const int* in_sizes, int n_in,
                              void* d_out, int out_size, void* d_ws, size_t ws_size,
                              hipStream_t stream) {
    const float* src  = (const float*)d_in[0];   // pc_source [B,N,3]
    const float* tgt  = (const float*)d_in[1];   // pc_target [B,M,3]
    const float* flow = (const float*)d_in[2];   // pred_flow [B,N,3]
    float* out = (float*)d_out;

    const int B = 2;                              // per reference setup
    const int N = in_sizes[0] / (B * 3);
    const int M = in_sizes[1] / (B * 3);
    const int BN = B * N, BM = B * M;
    const int T = 2 * (N + M);                    // total query instances

    // workspace layout: pred4 | tgt4 | topk | tickets
    float4* pred4 = (float4*)d_ws;
    float4* tgt4  = pred4 + BN;
    float*  topk  = (float*)(tgt4 + BM);          // NSLICE*16*T floats
    int*    tickets = (int*)(topk + (size_t)NSLICE * 16 * T);

    int maxq = (N > M) ? N : M;
    int gx = (maxq + BT - 1) / BT;                // q-chunks
    int nkeys = 2 * B * gx;                       // tickets per (z, qchunk)

    int maxBP = (BN > BM) ? BN : BM;
    int pgrid = (maxBP + 255) / 256;
    if (pgrid * 256 < nkeys) pgrid = (nkeys + 255) / 256;
    pack_kernel<<<pgrid, 256, 0, stream>>>(
        src, tgt, flow, pred4, tgt4, out, tickets, nkeys, BN, BM);

    float scale = 1.0f / ((float)B * (float)N);
    dim3 grid1(gx, NSLICE, 2 * B);
    knn_slice_kernel<<<grid1, BT, 0, stream>>>(
        pred4, tgt4, topk, tickets, out, N, M, T, scale);
}

// Round 13
// 170.791 us; speedup vs baseline: 1.4264x; 1.4264x over previous
//
#include <hip/hip_runtime.h>
#include <math.h>

// Chamfer k-NN (k=16, L2), R12: R10 revert (256-thr blocks, nslice=8,
// separate merge dispatch) + HYBRID ref fetch: even 8-ref groups read via
// scalarized s_load (SMEM/K$ pipe), odd groups from an LDS-staged half-tile
// (ds_read_b128 broadcast) -- two independent pipes each carrying half the
// candidate stream, interleaved within each loop iteration.
// R11 lesson: >4 scalar ref streams/CU thrash the K$ (FETCH 3x, VALUBusy 41%).

#define INFV    3.0e38f
#define NSLICE  8
#define QDEPTH  32
#define HTILE   512         // odd-group refs staged in LDS (half of 1024 slice)

__device__ __forceinline__ void ce(float& a, float& b) {
    float lo = fminf(a, b);
    b = fmaxf(a, b);
    a = lo;
}

// bitonic merge-sort of a bitonic 16-seq (stages 8,4,2,1 = 32 CE), ascending
__device__ __forceinline__ void bitonic16(float (&s)[16]) {
    ce(s[0],s[8]);  ce(s[1],s[9]);  ce(s[2],s[10]); ce(s[3],s[11]);
    ce(s[4],s[12]); ce(s[5],s[13]); ce(s[6],s[14]); ce(s[7],s[15]);
    ce(s[0],s[4]);  ce(s[1],s[5]);  ce(s[2],s[6]);  ce(s[3],s[7]);
    ce(s[8],s[12]); ce(s[9],s[13]); ce(s[10],s[14]);ce(s[11],s[15]);
    ce(s[0],s[2]);  ce(s[1],s[3]);  ce(s[4],s[6]);  ce(s[5],s[7]);
    ce(s[8],s[10]); ce(s[9],s[11]); ce(s[12],s[14]);ce(s[13],s[15]);
    ce(s[0],s[1]);  ce(s[2],s[3]);  ce(s[4],s[5]);  ce(s[6],s[7]);
    ce(s[8],s[9]);  ce(s[10],s[11]);ce(s[12],s[13]);ce(s[14],s[15]);
}

// Merge up to 8 queued values (qb[(base+i)*256], i<cnt-base) into sorted s[16].
__device__ __forceinline__ void drain_batch(float (&s)[16], const float* qb,
                                            int base, int cnt)
{
    float q[8];
#pragma unroll
    for (int i = 0; i < 8; ++i) {
        float v = qb[(base + i) * 256];
        q[i] = (base + i < cnt) ? v : INFV;
    }
    // sort8 ascending — Batcher odd-even, 19 CE
    ce(q[0],q[1]); ce(q[2],q[3]); ce(q[4],q[5]); ce(q[6],q[7]);
    ce(q[0],q[2]); ce(q[1],q[3]); ce(q[4],q[6]); ce(q[5],q[7]);
    ce(q[1],q[2]); ce(q[5],q[6]);
    ce(q[0],q[4]); ce(q[1],q[5]); ce(q[2],q[6]); ce(q[3],q[7]);
    ce(q[2],q[4]); ce(q[3],q[5]);
    ce(q[1],q[2]); ce(q[3],q[4]); ce(q[5],q[6]);
    // bitonic halver vs sorted s[16]: s[8+i] = min(s[8+i], q[7-i]) -> bitonic
#pragma unroll
    for (int i = 0; i < 8; ++i) s[8 + i] = fminf(s[8 + i], q[7 - i]);
    bitonic16(s);
}

__global__ __launch_bounds__(256) void pack_kernel(
    const float* __restrict__ src, const float* __restrict__ tgt,
    const float* __restrict__ flow,
    float4* __restrict__ pred4, float4* __restrict__ tgt4,
    float* __restrict__ out, int BN, int BM)
{
    int i = blockIdx.x * 256 + threadIdx.x;
    if (i == 0) out[0] = 0.0f;                 // replaces memset (poisoned 0xAA)
    if (i < BN) {
        float x = src[3 * i + 0] + flow[3 * i + 0];
        float y = src[3 * i + 1] + flow[3 * i + 1];
        float z = src[3 * i + 2] + flow[3 * i + 2];
        pred4[i] = make_float4(x, y, z, fmaf(x, x, fmaf(y, y, z * z)));
    }
    if (i < BM) {
        float x = tgt[3 * i + 0];
        float y = tgt[3 * i + 1];
        float z = tgt[3 * i + 2];
        tgt4[i] = make_float4(x, y, z, fmaf(x, x, fmaf(y, y, z * z)));
    }
}

__global__ __launch_bounds__(256, 4) void knn_slice_kernel(
    const float4* __restrict__ pred4,  // [B][N] (x,y,z,|p|^2)
    const float4* __restrict__ tgt4,   // [B][M]
    float* __restrict__ topk,          // [NSLICE][16][T], true d2, sorted asc
    int N, int M, int T)
{
    __shared__ float4 tile[HTILE];        //  8 KB: odd-group refs
    __shared__ float  qbuf[QDEPTH * 256]; // 32 KB: per-thread queues, stride 256

    const int tid   = threadIdx.x;
    const int slice = blockIdx.y;
    const int z     = blockIdx.z;          // b*2 + dir
    const int b     = z >> 1, dir = z & 1;

    const int nq   = dir ? M : N;
    const int nref = dir ? N : M;
    const int qi   = blockIdx.x * 256 + tid;
    const long instBase = (long)((z >= 1 ? N : 0) + (z >= 2 ? M : 0) + (z >= 3 ? N : 0));

    const float4* qp = (dir ? tgt4 : pred4) + (size_t)b * nq;
    const float4* rp = (dir ? pred4 : tgt4) + (size_t)b * nref;

    const int slen = nref / NSLICE;
    const int base = slice * slen;
    const int jend = (slice == NSLICE - 1) ? (nref - base) : slen;
    const float4* rs = rp + base;          // wave-uniform ref stream -> s_load

    // npairs [even s_load group, odd LDS group] of 8 refs each
    const int npairs = jend >> 4;

    // ---- stage odd groups into LDS: tile[p*8+u] = rs[(2p+1)*8+u] ----
    for (int i = tid; i < npairs * 8; i += 256)
        tile[i] = rs[((i >> 3) * 2 + 1) * 8 + (i & 7)];

    const bool valid = qi < nq;
    float nx = 0.f, ny = 0.f, nz = 0.f, q2 = 0.f;
    if (valid) {
        float4 q = qp[qi];
        nx = -2.0f * q.x; ny = -2.0f * q.y; nz = -2.0f * q.z; q2 = q.w;
    }
    __syncthreads();

    float s[16];
#pragma unroll
    for (int i = 0; i < 16; ++i) s[i] = INFV;
    float tau = valid ? INFV : -INFV;      // invalid lanes never enqueue
    int   cnt = 0;
    const float* qb_tid = qbuf + tid;

    auto dist = [&](const float4& p) -> float {
        return fmaf(nx, p.x, fmaf(ny, p.y, fmaf(nz, p.z, p.w)));
    };

#define DRAIN_ALL() {                                               \
        drain_batch(s, qb_tid, 0, cnt);                             \
        if (__ballot(cnt >  8)) drain_batch(s, qb_tid,  8, cnt);    \
        if (__ballot(cnt > 16)) drain_batch(s, qb_tid, 16, cnt);    \
        if (__ballot(cnt > 24)) drain_batch(s, qb_tid, 24, cnt);    \
        cnt = 0;                                                    \
        tau = valid ? s[15] : -INFV;                                \
    }

#define ENQ(c) { qbuf[cnt * 256 + tid] = (c); cnt += ((c) < tau) ? 1 : 0; }

#define QUAD(w0, w1, w2, w3) {                                      \
        float c0 = dist(w0), c1 = dist(w1);                         \
        float c2 = dist(w2), c3 = dist(w3);                         \
        float m = fminf(fminf(c0, c1), fminf(c2, c3));              \
        if (m < tau) { ENQ(c0) ENQ(c1) ENQ(c2) ENQ(c3) }           \
    }

#define PROC8(w) {                                                  \
        QUAD(w[0], w[1], w[2], w[3])                                \
        QUAD(w[4], w[5], w[6], w[7])                                \
        if (__ballot(cnt >= QDEPTH - 7)) DRAIN_ALL();               \
    }

    for (int p = 0; p < npairs; ++p) {
        float4 wA[8], wB[8];
        const float4* gp = rs + (size_t)p * 16;       // even group: s_load
#pragma unroll
        for (int u = 0; u < 8; ++u) wA[u] = gp[u];
        const float4* tp = tile + (size_t)p * 8;      // odd group: ds_read
#pragma unroll
        for (int u = 0; u < 8; ++u) wB[u] = tp[u];
        PROC8(wA)
        PROC8(wB)
    }
    for (int j = npairs * 16; j < jend; ++j) {        // generic tail
        float4 r = rs[j];
        float c = dist(r);
        if (c < tau) ENQ(c)
        if (__ballot(cnt >= QDEPTH - 7)) DRAIN_ALL();
    }
    if (__ballot(cnt > 0)) DRAIN_ALL();               // final

#undef PROC8
#undef QUAD
#undef ENQ
#undef DRAIN_ALL

    if (valid) {
        // transposed layout: topk[(slice*16 + i)*T + inst] — lane-coalesced
        float* o = topk + (size_t)slice * 16 * T + (instBase + qi);
#pragma unroll
        for (int i = 0; i < 16; ++i) o[(size_t)i * T] = s[i] + q2;  // true d2
    }
}

__global__ __launch_bounds__(256) void merge_topk_kernel(
    const float* __restrict__ topk, float* __restrict__ out,
    int T, float scale)
{
    const int inst = blockIdx.x * 256 + threadIdx.x;
    float acc = 0.0f;
    if (inst < T) {
        float s[16];
#pragma unroll
        for (int i = 0; i < 16; ++i)
            s[i] = topk[(size_t)i * T + inst];        // slice 0, sorted asc
        for (int sl = 1; sl < NSLICE; ++sl) {
            const float* q = topk + (size_t)sl * 16 * T + inst;
#pragma unroll
            for (int i = 0; i < 16; ++i)
                s[i] = fminf(s[i], q[(size_t)(15 - i) * T]);  // bitonic halver
            if (sl < NSLICE - 1) bitonic16(s);        // prep next halver
        }
        float sum = 0.0f;
#pragma unroll
        for (int i = 0; i < 16; ++i) sum += sqrtf(fmaxf(s[i], 0.0f));
        acc = sum * (1.0f / 16.0f);
    }
#pragma unroll
    for (int off = 32; off > 0; off >>= 1) acc += __shfl_down(acc, off);
    __shared__ float wsum[4];
    const int lane = threadIdx.x & 63, wid = threadIdx.x >> 6;
    if (lane == 0) wsum[wid] = acc;
    __syncthreads();
    if (threadIdx.x == 0)
        atomicAdd(out, (wsum[0] + wsum[1] + wsum[2] + wsum[3]) * scale);
}

extern "C" void kernel_launch(void* const* d_in, const int* in_sizes, int n_in,
                              void* d_out, int out_size, void* d_ws, size_t ws_size,
                              hipStream_t stream) {
    const float* src  = (const float*)d_in[0];   // pc_source [B,N,3]
    const float* tgt  = (const float*)d_in[1];   // pc_target [B,M,3]
    const float* flow = (const float*)d_in[2];   // pred_flow [B,N,3]
    float* out = (float*)d_out;

    const int B = 2;                              // per reference setup
    const int N = in_sizes[0] / (B * 3);
    const int M = in_sizes[1] / (B * 3);
    const int BN = B * N, BM = B * M;
    const int T = 2 * (N + M);                    // total query instances

    // workspace layout: pred4 | tgt4 | topk
    float4* pred4 = (float4*)d_ws;
    float4* tgt4  = pred4 + BN;
    float*  topk  = (float*)(tgt4 + BM);          // NSLICE*16*T floats

    int maxBP = (BN > BM) ? BN : BM;
    pack_kernel<<<(maxBP + 255) / 256, 256, 0, stream>>>(
        src, tgt, flow, pred4, tgt4, out, BN, BM);

    int maxq = (N > M) ? N : M;
    dim3 grid1((maxq + 255) / 256, NSLICE, 2 * B);
    knn_slice_kernel<<<grid1, 256, 0, stream>>>(pred4, tgt4, topk, N, M, T);

    float scale = 1.0f / ((float)B * (float)N);
    merge_topk_kernel<<<(T + 255) / 256, 256, 0, stream>>>(topk, out, T, scale);
}

// Round 14
// 158.798 us; speedup vs baseline: 1.5341x; 1.0755x over previous
//
#include <hip/hip_runtime.h>
#include <math.h>

// Chamfer k-NN (k=16, L2), R13: FULLY BRANCHLESS candidate path.
// R12 post-mortem: at wave64, a divergent if-body executes whenever ANY of 64
// lanes takes it (P ~ 1-(1-p)^64 ~ 60-70%), so the QUAD gate + exec-mask
// machinery ADDED wave-wide instructions. Honest branchless cost per cand:
// 3 FMA + addr + ds_write + cmp + addc = 6 VALU, no SALU churn.
// Refs via s_load (LDS pipe stays write-only); 32-deep LDS queue,
// conflict-free (stride 256); batched bitonic drains on every-8 ballot.
// kernel0 (pack): pred4=(src+flow,|.|^2), tgt4=(tgt,|.|^2); zeroes out[0].
// kernel2 (merge): bitonic merge of 8 sorted 16-lists, sqrt, mean, atomic.

#define INFV    3.0e38f
#define NSLICE  8
#define QDEPTH  32

__device__ __forceinline__ void ce(float& a, float& b) {
    float lo = fminf(a, b);
    b = fmaxf(a, b);
    a = lo;
}

// bitonic merge-sort of a bitonic 16-seq (stages 8,4,2,1 = 32 CE), ascending
__device__ __forceinline__ void bitonic16(float (&s)[16]) {
    ce(s[0],s[8]);  ce(s[1],s[9]);  ce(s[2],s[10]); ce(s[3],s[11]);
    ce(s[4],s[12]); ce(s[5],s[13]); ce(s[6],s[14]); ce(s[7],s[15]);
    ce(s[0],s[4]);  ce(s[1],s[5]);  ce(s[2],s[6]);  ce(s[3],s[7]);
    ce(s[8],s[12]); ce(s[9],s[13]); ce(s[10],s[14]);ce(s[11],s[15]);
    ce(s[0],s[2]);  ce(s[1],s[3]);  ce(s[4],s[6]);  ce(s[5],s[7]);
    ce(s[8],s[10]); ce(s[9],s[11]); ce(s[12],s[14]);ce(s[13],s[15]);
    ce(s[0],s[1]);  ce(s[2],s[3]);  ce(s[4],s[5]);  ce(s[6],s[7]);
    ce(s[8],s[9]);  ce(s[10],s[11]);ce(s[12],s[13]);ce(s[14],s[15]);
}

// Merge up to 8 queued values (qb[(base+i)*256], i<cnt-base) into sorted s[16].
__device__ __forceinline__ void drain_batch(float (&s)[16], const float* qb,
                                            int base, int cnt)
{
    float q[8];
#pragma unroll
    for (int i = 0; i < 8; ++i) {
        float v = qb[(base + i) * 256];
        q[i] = (base + i < cnt) ? v : INFV;
    }
    // sort8 ascending — Batcher odd-even, 19 CE
    ce(q[0],q[1]); ce(q[2],q[3]); ce(q[4],q[5]); ce(q[6],q[7]);
    ce(q[0],q[2]); ce(q[1],q[3]); ce(q[4],q[6]); ce(q[5],q[7]);
    ce(q[1],q[2]); ce(q[5],q[6]);
    ce(q[0],q[4]); ce(q[1],q[5]); ce(q[2],q[6]); ce(q[3],q[7]);
    ce(q[2],q[4]); ce(q[3],q[5]);
    ce(q[1],q[2]); ce(q[3],q[4]); ce(q[5],q[6]);
    // bitonic halver vs sorted s[16]: s[8+i] = min(s[8+i], q[7-i]) -> bitonic
#pragma unroll
    for (int i = 0; i < 8; ++i) s[8 + i] = fminf(s[8 + i], q[7 - i]);
    bitonic16(s);
}

__global__ __launch_bounds__(256) void pack_kernel(
    const float* __restrict__ src, const float* __restrict__ tgt,
    const float* __restrict__ flow,
    float4* __restrict__ pred4, float4* __restrict__ tgt4,
    float* __restrict__ out, int BN, int BM)
{
    int i = blockIdx.x * 256 + threadIdx.x;
    if (i == 0) out[0] = 0.0f;                 // replaces memset (poisoned 0xAA)
    if (i < BN) {
        float x = src[3 * i + 0] + flow[3 * i + 0];
        float y = src[3 * i + 1] + flow[3 * i + 1];
        float z = src[3 * i + 2] + flow[3 * i + 2];
        pred4[i] = make_float4(x, y, z, fmaf(x, x, fmaf(y, y, z * z)));
    }
    if (i < BM) {
        float x = tgt[3 * i + 0];
        float y = tgt[3 * i + 1];
        float z = tgt[3 * i + 2];
        tgt4[i] = make_float4(x, y, z, fmaf(x, x, fmaf(y, y, z * z)));
    }
}

__global__ __launch_bounds__(256, 4) void knn_slice_kernel(
    const float4* __restrict__ pred4,  // [B][N] (x,y,z,|p|^2)
    const float4* __restrict__ tgt4,   // [B][M]
    float* __restrict__ topk,          // [NSLICE][16][T], true d2, sorted asc
    int N, int M, int T)
{
    __shared__ float qbuf[QDEPTH * 256];  // 32 KB per-thread queues, stride 256

    const int tid   = threadIdx.x;
    const int slice = blockIdx.y;
    const int z     = blockIdx.z;          // b*2 + dir
    const int b     = z >> 1, dir = z & 1;

    const int nq   = dir ? M : N;
    const int nref = dir ? N : M;
    const int qi   = blockIdx.x * 256 + tid;
    const long instBase = (long)((z >= 1 ? N : 0) + (z >= 2 ? M : 0) + (z >= 3 ? N : 0));

    const float4* qp = (dir ? tgt4 : pred4) + (size_t)b * nq;
    const float4* rp = (dir ? pred4 : tgt4) + (size_t)b * nref;

    const int slen = nref / NSLICE;
    const int base = slice * slen;
    const int jend = (slice == NSLICE - 1) ? (nref - base) : slen;
    const float4* rs = rp + base;          // wave-uniform ref stream -> s_load

    const bool valid = qi < nq;
    float nx = 0.f, ny = 0.f, nz = 0.f, q2 = 0.f;
    if (valid) {
        float4 q = qp[qi];
        nx = -2.0f * q.x; ny = -2.0f * q.y; nz = -2.0f * q.z; q2 = q.w;
    }

    float s[16];
#pragma unroll
    for (int i = 0; i < 16; ++i) s[i] = INFV;
    float tau = valid ? INFV : -INFV;      // invalid lanes never count enqueues
    int   cnt = 0;
    const float* qb_tid = qbuf + tid;

    auto dist = [&](const float4& p) -> float {
        return fmaf(nx, p.x, fmaf(ny, p.y, fmaf(nz, p.z, p.w)));
    };

#define DRAIN_ALL() {                                               \
        drain_batch(s, qb_tid, 0, cnt);                             \
        if (__ballot(cnt >  8)) drain_batch(s, qb_tid,  8, cnt);    \
        if (__ballot(cnt > 16)) drain_batch(s, qb_tid, 16, cnt);    \
        if (__ballot(cnt > 24)) drain_batch(s, qb_tid, 24, cnt);    \
        cnt = 0;                                                    \
        tau = valid ? s[15] : -INFV;                                \
    }

    // branchless: unconditional slot write, predicated count advance.
    // qbuf[cnt*256+tid]: bank = tid%32 regardless of divergent cnt -> 0 conflicts
#define STEP(w) {                                                   \
        float c = dist(w);                                          \
        qbuf[cnt * 256 + tid] = c;                                  \
        cnt += (c < tau) ? 1 : 0;                                   \
    }

#define PROC8(w) {                                                  \
        STEP(w[0]) STEP(w[1]) STEP(w[2]) STEP(w[3])                 \
        STEP(w[4]) STEP(w[5]) STEP(w[6]) STEP(w[7])                 \
        if (__ballot(cnt >= QDEPTH - 7)) DRAIN_ALL();               \
    }

    const int ngrp = jend >> 3;
    const int gmax = ngrp & ~1;            // even count for the 2x-unrolled loop
    float4 wA[8], wB[8];                   // scalarized -> SGPR tuples
    if (gmax > 0) {
#pragma unroll
        for (int u = 0; u < 8; ++u) wA[u] = rs[u];
        for (int g = 0; g < gmax; g += 2) {
            {   // prefetch group g+1 (uniform addr -> s_load) during group g
                const float4* tp = rs + (size_t)(g + 1) * 8;
#pragma unroll
                for (int u = 0; u < 8; ++u) wB[u] = tp[u];
            }
            PROC8(wA)
            {   // prefetch group g+2 (clamped) during group g+1
                const float4* tp = rs + (size_t)((g + 2 < gmax) ? g + 2 : g) * 8;
#pragma unroll
                for (int u = 0; u < 8; ++u) wA[u] = tp[u];
            }
            PROC8(wB)
        }
    }
    for (int j = gmax * 8; j < jend; ++j) {    // generic tail
        float4 r = rs[j];
        STEP(r)
        if (__ballot(cnt >= QDEPTH - 7)) DRAIN_ALL();
    }
    if (__ballot(cnt > 0)) DRAIN_ALL();        // final

#undef PROC8
#undef STEP
#undef DRAIN_ALL

    if (valid) {
        // transposed layout: topk[(slice*16 + i)*T + inst] — lane-coalesced
        float* o = topk + (size_t)slice * 16 * T + (instBase + qi);
#pragma unroll
        for (int i = 0; i < 16; ++i) o[(size_t)i * T] = s[i] + q2;  // true d2
    }
}

__global__ __launch_bounds__(256) void merge_topk_kernel(
    const float* __restrict__ topk, float* __restrict__ out,
    int T, float scale)
{
    const int inst = blockIdx.x * 256 + threadIdx.x;
    float acc = 0.0f;
    if (inst < T) {
        float s[16];
#pragma unroll
        for (int i = 0; i < 16; ++i)
            s[i] = topk[(size_t)i * T + inst];        // slice 0, sorted asc
        for (int sl = 1; sl < NSLICE; ++sl) {
            const float* q = topk + (size_t)sl * 16 * T + inst;
#pragma unroll
            for (int i = 0; i < 16; ++i)
                s[i] = fminf(s[i], q[(size_t)(15 - i) * T]);  // bitonic halver
            if (sl < NSLICE - 1) bitonic16(s);        // prep next halver
        }
        float sum = 0.0f;
#pragma unroll
        for (int i = 0; i < 16; ++i) sum += sqrtf(fmaxf(s[i], 0.0f));
        acc = sum * (1.0f / 16.0f);
    }
#pragma unroll
    for (int off = 32; off > 0; off >>= 1) acc += __shfl_down(acc, off);
    __shared__ float wsum[4];
    const int lane = threadIdx.x & 63, wid = threadIdx.x >> 6;
    if (lane == 0) wsum[wid] = acc;
    __syncthreads();
    if (threadIdx.x == 0)
        atomicAdd(out, (wsum[0] + wsum[1] + wsum[2] + wsum[3]) * scale);
}

extern "C" void kernel_launch(void* const* d_in, const int* in_sizes, int n_in,
                              void* d_out, int out_size, void* d_ws, size_t ws_size,
                              hipStream_t stream) {
    const float* src  = (const float*)d_in[0];   // pc_source [B,N,3]
    const float* tgt  = (const float*)d_in[1];   // pc_target [B,M,3]
    const float* flow = (const float*)d_in[2];   // pred_flow [B,N,3]
    float* out = (float*)d_out;

    const int B = 2;                              // per reference setup
    const int N = in_sizes[0] / (B * 3);
    const int M = in_sizes[1] / (B * 3);
    const int BN = B * N, BM = B * M;
    const int T = 2 * (N + M);                    // total query instances

    // workspace layout: pred4 | tgt4 | topk
    float4* pred4 = (float4*)d_ws;
    float4* tgt4  = pred4 + BN;
    float*  topk  = (float*)(tgt4 + BM);          // NSLICE*16*T floats

    int maxBP = (BN > BM) ? BN : BM;
    pack_kernel<<<(maxBP + 255) / 256, 256, 0, stream>>>(
        src, tgt, flow, pred4, tgt4, out, BN, BM);

    int maxq = (N > M) ? N : M;
    dim3 grid1((maxq + 255) / 256, NSLICE, 2 * B);
    knn_slice_kernel<<<grid1, 256, 0, stream>>>(pred4, tgt4, topk, N, M, T);

    float scale = 1.0f / ((float)B * (float)N);
    merge_topk_kernel<<<(T + 255) / 256, 256, 0, stream>>>(topk, out, T, scale);
}